// Round 1
// baseline (5056.638 us; speedup 1.0000x reference)
//
#include <hip/hip_runtime.h>
#include <cstdint>
#include <cstddef>

// Problem constants
constexpr int Bc   = 2;
constexpr int Sc   = 2048;
constexpr int Dm   = 768;
constexpr int Hc   = 12;
constexpr int HD   = 64;
constexpr int DI   = 1536;
constexpr int NST  = 16;
constexpr int DTR  = 48;
constexpr int CAP  = 256;   // 0.125 * S
constexpr int DF   = 3072;
constexpr int M_   = Bc * Sc;  // 4096 tokens

// ---------------------------------------------------------------------------
// Activation codes: 0 none, 1 softplus, 2 sigmoid, 3 relu, 4 gelu(exact)
__device__ __forceinline__ float apply_act(float v, int act) {
    switch (act) {
        case 1: return (v > 20.f) ? v : log1pf(__expf(v));
        case 2: return 1.f / (1.f + __expf(-v));
        case 3: return fmaxf(v, 0.f);
        case 4: return 0.5f * v * (1.f + erff(v * 0.70710678118654752f));
        default: return v;
    }
}

// ---------------------------------------------------------------------------
// Generic fp32 GEMM: C[M,N] = act(acc*C + A[M,K](lda) @ W[K,N] + bias)
// BM=BN=128, BK=16, 256 threads, 8x8 microtile (split 4+4 to avoid LDS bank
// 4-way conflicts). K must be a multiple of 16, M a multiple of 128.
__global__ __launch_bounds__(256) void gemm_kernel(
    const float* __restrict__ A, int lda,
    const float* __restrict__ W,
    const float* __restrict__ bias,
    float* __restrict__ C,
    int M, int N, int K, int act, int accflag)
{
    __shared__ float As[16][132];
    __shared__ float Bs[16][132];
    const int tid = threadIdx.x;
    const int bm = blockIdx.y * 128;
    const int bn = blockIdx.x * 128;
    const int tx = tid & 15, ty = tid >> 4;

    float acc[8][8];
#pragma unroll
    for (int i = 0; i < 8; ++i)
#pragma unroll
        for (int j = 0; j < 8; ++j) acc[i][j] = 0.f;

    for (int k0 = 0; k0 < K; k0 += 16) {
        // A tile: 128 rows x 16 k  (transposed into As[k][m])
#pragma unroll
        for (int i = 0; i < 2; ++i) {
            int f = tid + 256 * i;
            int row = f >> 2;
            int kc = (f & 3) * 4;
            const float* ap = A + (size_t)(bm + row) * lda + (k0 + kc);
            float4 v = *(const float4*)ap;
            As[kc + 0][row] = v.x; As[kc + 1][row] = v.y;
            As[kc + 2][row] = v.z; As[kc + 3][row] = v.w;
        }
        // B tile: 16 k x 128 cols (ragged-N guarded)
#pragma unroll
        for (int i = 0; i < 2; ++i) {
            int f = tid + 256 * i;
            int row = f >> 5;
            int col = (f & 31) * 4;
            int gn = bn + col;
            const float* wp = W + (size_t)(k0 + row) * N + gn;
            float4 v;
            if (gn + 3 < N) v = *(const float4*)wp;
            else {
                v.x = (gn + 0 < N) ? wp[0] : 0.f;
                v.y = (gn + 1 < N) ? wp[1] : 0.f;
                v.z = (gn + 2 < N) ? wp[2] : 0.f;
                v.w = (gn + 3 < N) ? wp[3] : 0.f;
            }
            *(float4*)&Bs[row][col] = v;
        }
        __syncthreads();
#pragma unroll
        for (int kk = 0; kk < 16; ++kk) {
            float a[8], b[8];
            *(float4*)&a[0] = *(const float4*)&As[kk][ty * 4];
            *(float4*)&a[4] = *(const float4*)&As[kk][64 + ty * 4];
            *(float4*)&b[0] = *(const float4*)&Bs[kk][tx * 4];
            *(float4*)&b[4] = *(const float4*)&Bs[kk][64 + tx * 4];
#pragma unroll
            for (int i = 0; i < 8; ++i)
#pragma unroll
                for (int j = 0; j < 8; ++j)
                    acc[i][j] = fmaf(a[i], b[j], acc[i][j]);
        }
        __syncthreads();
    }

#pragma unroll
    for (int ii = 0; ii < 8; ++ii) {
        int row = bm + ((ii < 4) ? (ty * 4 + ii) : (64 + ty * 4 + ii - 4));
#pragma unroll
        for (int jj = 0; jj < 8; ++jj) {
            int col = bn + ((jj < 4) ? (tx * 4 + jj) : (64 + tx * 4 + jj - 4));
            if (col < N) {
                size_t cidx = (size_t)row * N + col;
                float v = acc[ii][jj];
                if (accflag) v += C[cidx];
                if (bias) v += bias[col];
                C[cidx] = apply_act(v, act);
            }
        }
    }
}

// ---------------------------------------------------------------------------
// LayerNorm: one block per token row (768 = 3*256)
__global__ __launch_bounds__(256) void ln_kernel(
    const float* __restrict__ x, const float* __restrict__ w,
    const float* __restrict__ b, float* __restrict__ out)
{
    const int row = blockIdx.x, tid = threadIdx.x;
    const float* xp = x + (size_t)row * Dm;
    float v0 = xp[tid], v1 = xp[tid + 256], v2 = xp[tid + 512];
    float s1 = v0 + v1 + v2;
    float s2 = v0 * v0 + v1 * v1 + v2 * v2;
#pragma unroll
    for (int off = 32; off; off >>= 1) {
        s1 += __shfl_down(s1, off, 64);
        s2 += __shfl_down(s2, off, 64);
    }
    __shared__ float r1[4], r2[4];
    int wid = tid >> 6, lane = tid & 63;
    if (lane == 0) { r1[wid] = s1; r2[wid] = s2; }
    __syncthreads();
    s1 = r1[0] + r1[1] + r1[2] + r1[3];
    s2 = r2[0] + r2[1] + r2[2] + r2[3];
    float mu = s1 * (1.f / 768.f);
    float var = s2 * (1.f / 768.f) - mu * mu;
    float rstd = rsqrtf(var + 1e-5f);
    float* op = out + (size_t)row * Dm;
    op[tid]       = (v0 - mu) * rstd * w[tid]       + b[tid];
    op[tid + 256] = (v1 - mu) * rstd * w[tid + 256] + b[tid + 256];
    op[tid + 512] = (v2 - mu) * rstd * w[tid + 512] + b[tid + 512];
}

// ---------------------------------------------------------------------------
// In-place RoPE on q and k slices of qkv (B,S,2304). One thread per (b,s,h,i<32)
__global__ __launch_bounds__(256) void rope_kernel(float* __restrict__ qkv)
{
    int id = blockIdx.x * 256 + threadIdx.x;   // B*S*H*32
    int i = id & 31;
    int h = (id >> 5) % Hc;
    int r = id / (32 * Hc);        // b*S + s
    int s = r & (Sc - 1);
    float inv = powf(10000.f, -(float)(2 * i) * (1.f / 64.f));
    float f = (float)s * inv;
    float sn, cs;
    sincosf(f, &sn, &cs);
    float* base = qkv + (size_t)r * 2304 + h * 64 + i;
    float q1 = base[0], q2 = base[32];
    base[0]  = q1 * cs - q2 * sn;
    base[32] = q1 * sn + q2 * cs;
    float* kb = base + Dm;
    float k1 = kb[0], k2 = kb[32];
    kb[0]  = k1 * cs - k2 * sn;
    kb[32] = k1 * sn + k2 * cs;
}

// ---------------------------------------------------------------------------
// Attention: 1 query per thread (q,o in regs), 64-key LDS tiles, online softmax
__global__ __launch_bounds__(64) void attn_kernel(
    const float* __restrict__ qkv, float* __restrict__ ao)
{
    __shared__ float Kt[64][64];
    __shared__ float Vt[64][64];
    const int tid = threadIdx.x;
    const int bh = blockIdx.y;
    const int b = bh / Hc;
    const int h = bh % Hc;
    const int s = blockIdx.x * 64 + tid;
    const float* qp = qkv + ((size_t)(b * Sc + s)) * 2304 + h * 64;
    float q[64];
#pragma unroll
    for (int i = 0; i < 16; ++i) {
        float4 t = *(const float4*)(qp + i * 4);
        q[4 * i + 0] = t.x * 0.125f; q[4 * i + 1] = t.y * 0.125f;
        q[4 * i + 2] = t.z * 0.125f; q[4 * i + 3] = t.w * 0.125f;
    }
    float o[64];
#pragma unroll
    for (int i = 0; i < 64; ++i) o[i] = 0.f;
    float m = -1e30f, l = 0.f;

    for (int kt = 0; kt < Sc; kt += 64) {
#pragma unroll
        for (int i = 0; i < 16; ++i) {
            int f = tid + 64 * i;
            int row = f >> 4;
            int c4 = (f & 15) * 4;
            const float* kp = qkv + ((size_t)(b * Sc + kt + row)) * 2304 + Dm + h * 64 + c4;
            *(float4*)&Kt[row][c4] = *(const float4*)kp;
            *(float4*)&Vt[row][c4] = *(const float4*)(kp + Dm);
        }
        __syncthreads();
        for (int j = 0; j < 64; ++j) {
            float d0 = 0.f, d1 = 0.f, d2 = 0.f, d3 = 0.f;
#pragma unroll
            for (int c = 0; c < 4; ++c) {
                float4 k0 = *(const float4*)&Kt[j][c * 16];
                float4 k1 = *(const float4*)&Kt[j][c * 16 + 4];
                float4 k2 = *(const float4*)&Kt[j][c * 16 + 8];
                float4 k3 = *(const float4*)&Kt[j][c * 16 + 12];
                d0 += q[c*16+0]*k0.x + q[c*16+1]*k0.y + q[c*16+2]*k0.z + q[c*16+3]*k0.w;
                d1 += q[c*16+4]*k1.x + q[c*16+5]*k1.y + q[c*16+6]*k1.z + q[c*16+7]*k1.w;
                d2 += q[c*16+8]*k2.x + q[c*16+9]*k2.y + q[c*16+10]*k2.z + q[c*16+11]*k2.w;
                d3 += q[c*16+12]*k3.x + q[c*16+13]*k3.y + q[c*16+14]*k3.z + q[c*16+15]*k3.w;
            }
            float dot = (d0 + d1) + (d2 + d3);
            if (dot > m) {
                float corr = __expf(m - dot);
                l *= corr;
#pragma unroll
                for (int d = 0; d < 64; ++d) o[d] *= corr;
                m = dot;
            }
            float p = __expf(dot - m);
            l += p;
#pragma unroll
            for (int c = 0; c < 16; ++c) {
                float4 vv = *(const float4*)&Vt[j][c * 4];
                o[c*4+0] += p * vv.x; o[c*4+1] += p * vv.y;
                o[c*4+2] += p * vv.z; o[c*4+3] += p * vv.w;
            }
        }
        __syncthreads();
    }
    float rl = 1.f / l;
    float* op = ao + ((size_t)(b * Sc + s)) * Dm + h * 64;
#pragma unroll
    for (int i = 0; i < 16; ++i) {
        float4 t;
        t.x = o[4*i+0] * rl; t.y = o[4*i+1] * rl;
        t.z = o[4*i+2] * rl; t.w = o[4*i+3] * rl;
        *(float4*)(op + i * 4) = t;
    }
}

// ---------------------------------------------------------------------------
// Depthwise causal conv (KC=4) over xc = xz[..., :DI], then SiLU -> u
__global__ __launch_bounds__(256) void conv_silu_kernel(
    const float* __restrict__ xz, const float* __restrict__ cw,
    const float* __restrict__ cb, float* __restrict__ u)
{
    int id = blockIdx.x * 256 + threadIdx.x;   // B*S*DI
    int d = id % DI;
    int r = id / DI;           // b*S + s
    int s = r & (Sc - 1);
    int b = r >> 11;
    float acc = cb[d];
#pragma unroll
    for (int j = 0; j < 4; ++j) {
        int sp = s + j - 3;
        if (sp >= 0)
            acc += xz[((size_t)(b * Sc + sp)) * (2 * DI) + d] * cw[d * 4 + j];
    }
    u[id] = acc / (1.f + __expf(-acc));
}

// ---------------------------------------------------------------------------
// Selective scan: thread = (b, d, n). 16-lane shfl reduce for y. 8-deep prefetch.
__global__ __launch_bounds__(256) void scan_kernel(
    const float* __restrict__ delta, const float* __restrict__ u,
    const float* __restrict__ dbc, const float* __restrict__ A_log,
    const float* __restrict__ Dp, float* __restrict__ y)
{
    int gid = blockIdx.x * 256 + threadIdx.x;
    int n = gid & 15;
    int ch = gid >> 4;              // 0..3071
    int b = ch / DI;
    int dd = ch - b * DI;
    float Av = -__expf(A_log[dd * NST + n]);
    float Dv = Dp[dd];
    const float* dp = delta + (size_t)b * Sc * DI + dd;
    const float* up = u     + (size_t)b * Sc * DI + dd;
    const float* Bp = dbc   + (size_t)b * Sc * 80 + DTR + n;
    const float* Cp = Bp + NST;
    float* yp = y + (size_t)b * Sc * DI + dd;

    float h = 0.f;
    constexpr int CH = 8;
    float cdt[CH], cu[CH], cB[CH], cC[CH];
    float ndt[CH], nu[CH], nB[CH], nC[CH];
#pragma unroll
    for (int i = 0; i < CH; ++i) {
        cdt[i] = dp[(size_t)i * DI]; cu[i] = up[(size_t)i * DI];
        cB[i] = Bp[(size_t)i * 80];  cC[i] = Cp[(size_t)i * 80];
    }
    for (int t0 = 0; t0 < Sc; t0 += CH) {
        if (t0 + CH < Sc) {
#pragma unroll
            for (int i = 0; i < CH; ++i) {
                size_t t = t0 + CH + i;
                ndt[i] = dp[t * DI]; nu[i] = up[t * DI];
                nB[i] = Bp[t * 80];  nC[i] = Cp[t * 80];
            }
        }
#pragma unroll
        for (int i = 0; i < CH; ++i) {
            float dt = cdt[i];
            h = __expf(dt * Av) * h + dt * cu[i] * cB[i];
            float p = h * cC[i];
            p += __shfl_xor(p, 1, 16);
            p += __shfl_xor(p, 2, 16);
            p += __shfl_xor(p, 4, 16);
            p += __shfl_xor(p, 8, 16);
            if (n == 0) yp[(size_t)(t0 + i) * DI] = p + cu[i] * Dv;
        }
#pragma unroll
        for (int i = 0; i < CH; ++i) {
            cdt[i] = ndt[i]; cu[i] = nu[i]; cB[i] = nB[i]; cC[i] = nC[i];
        }
    }
}

// ---------------------------------------------------------------------------
// y *= silu(z),  z = xz[..., DI + d]
__global__ __launch_bounds__(256) void ssmin_kernel(
    float* __restrict__ y, const float* __restrict__ xz)
{
    int id = blockIdx.x * 256 + threadIdx.x;   // B*S*DI
    int d = id % DI;
    int r = id / DI;
    float z = xz[(size_t)r * (2 * DI) + DI + d];
    y[id] = y[id] * (z / (1.f + __expf(-z)));
}

// ---------------------------------------------------------------------------
// x1 = x + g*attn + (1-g)*ssm
__global__ __launch_bounds__(256) void x1_kernel(
    const float* __restrict__ x, const float* __restrict__ g,
    const float* __restrict__ at, const float* __restrict__ sm,
    float* __restrict__ x1)
{
    int id = blockIdx.x * 256 + threadIdx.x;
    float gv = g[id];
    x1[id] = x[id] + gv * at[id] + (1.f - gv) * sm[id];
}

// ---------------------------------------------------------------------------
// sc[t] = rh[t,:] . r_w2 + r_b2   (192 = 3*64, one wave per token)
__global__ __launch_bounds__(256) void rowdot_kernel(
    const float* __restrict__ rh, const float* __restrict__ w2,
    const float* __restrict__ b2, float* __restrict__ sc)
{
    int lane = threadIdx.x & 63;
    int t = blockIdx.x * 4 + (threadIdx.x >> 6);
    const float* rp = rh + (size_t)t * 192;
    float sum = rp[lane] * w2[lane] + rp[lane + 64] * w2[lane + 64]
              + rp[lane + 128] * w2[lane + 128];
#pragma unroll
    for (int off = 32; off; off >>= 1) sum += __shfl_down(sum, off, 64);
    if (lane == 0) sc[t] = sum + b2[0];
}

// ---------------------------------------------------------------------------
// Top-256 of 2048 per batch via iterative argmax (tie -> lowest index = jax)
__global__ __launch_bounds__(256) void topk_kernel(
    const float* __restrict__ sc, int* __restrict__ idxb)
{
    __shared__ float vals[Sc];
    __shared__ float rv[4];
    __shared__ int ri[4];
    const int b = blockIdx.x, tid = threadIdx.x;
    for (int i = tid; i < Sc; i += 256) vals[i] = sc[(size_t)b * Sc + i];
    __syncthreads();
    for (int it = 0; it < CAP; ++it) {
        float bv = -3.4e38f; int bi = 0x7fffffff;
        for (int i = tid; i < Sc; i += 256) {
            float v = vals[i];
            if (v > bv || (v == bv && i < bi)) { bv = v; bi = i; }
        }
#pragma unroll
        for (int off = 32; off; off >>= 1) {
            float ov = __shfl_down(bv, off, 64);
            int oi = __shfl_down(bi, off, 64);
            if (ov > bv || (ov == bv && oi < bi)) { bv = ov; bi = oi; }
        }
        int lane = tid & 63, wid = tid >> 6;
        if (lane == 0) { rv[wid] = bv; ri[wid] = bi; }
        __syncthreads();
        if (tid == 0) {
            float Bv = rv[0]; int Bi = ri[0];
            for (int w = 1; w < 4; ++w)
                if (rv[w] > Bv || (rv[w] == Bv && ri[w] < Bi)) { Bv = rv[w]; Bi = ri[w]; }
            idxb[b * CAP + it] = Bi;
            vals[Bi] = -3.4e38f;
        }
        __syncthreads();
    }
}

// ---------------------------------------------------------------------------
__global__ __launch_bounds__(256) void gather_kernel(
    const float* __restrict__ xn2, const int* __restrict__ idxb,
    float* __restrict__ Xsel)
{
    int i = blockIdx.x;            // 0..511
    int b = i >> 8;
    int t = idxb[i];
    const float* src = xn2 + ((size_t)(b * Sc + t)) * Dm;
    float* dst = Xsel + (size_t)i * Dm;
    int c = threadIdx.x;
    dst[c] = src[c]; dst[c + 256] = src[c + 256]; dst[c + 512] = src[c + 512];
}

__global__ __launch_bounds__(256) void finaladd_kernel(
    const float* __restrict__ x1, const float* __restrict__ xn2,
    float* __restrict__ out)
{
    int id = blockIdx.x * 256 + threadIdx.x;
    out[id] = x1[id] + xn2[id];
}

__global__ __launch_bounds__(256) void scatter_kernel(
    const float* __restrict__ x1, const float* __restrict__ proc,
    const int* __restrict__ idxb, float* __restrict__ out)
{
    int i = blockIdx.x;            // 0..511
    int b = i >> 8;
    int t = idxb[i];
    size_t ro = ((size_t)(b * Sc + t)) * Dm;
    const float* pp = proc + (size_t)i * Dm;
    int c = threadIdx.x;
    out[ro + c]       = x1[ro + c]       + pp[c];
    out[ro + c + 256] = x1[ro + c + 256] + pp[c + 256];
    out[ro + c + 512] = x1[ro + c + 512] + pp[c + 512];
}

// ---------------------------------------------------------------------------
extern "C" void kernel_launch(void* const* d_in, const int* in_sizes, int n_in,
                              void* d_out, int out_size, void* d_ws, size_t ws_size,
                              hipStream_t stream)
{
    (void)in_sizes; (void)n_in; (void)out_size; (void)ws_size;
    const float* x          = (const float*)d_in[0];
    const float* ln1_w      = (const float*)d_in[1];
    const float* ln1_b      = (const float*)d_in[2];
    const float* ln2_w      = (const float*)d_in[3];
    const float* ln2_b      = (const float*)d_in[4];
    const float* qkv_w      = (const float*)d_in[5];
    const float* attn_out_w = (const float*)d_in[6];
    const float* attn_out_b = (const float*)d_in[7];
    const float* in_proj_w  = (const float*)d_in[8];
    const float* conv_w     = (const float*)d_in[9];
    const float* conv_b     = (const float*)d_in[10];
    const float* x_proj_w   = (const float*)d_in[11];
    const float* dt_w       = (const float*)d_in[12];
    const float* dt_b       = (const float*)d_in[13];
    const float* A_log      = (const float*)d_in[14];
    const float* Dvec       = (const float*)d_in[15];
    const float* ssm_out_w  = (const float*)d_in[16];
    const float* gate_w     = (const float*)d_in[17];
    const float* gate_b     = (const float*)d_in[18];
    const float* ffn_w1     = (const float*)d_in[19];
    const float* ffn_b1     = (const float*)d_in[20];
    const float* ffn_w2     = (const float*)d_in[21];
    const float* ffn_b2     = (const float*)d_in[22];
    const float* r_w1       = (const float*)d_in[23];
    const float* r_b1       = (const float*)d_in[24];
    const float* r_w2       = (const float*)d_in[25];
    const float* r_b2       = (const float*)d_in[26];
    float* out = (float*)d_out;

    // Workspace layout (floats). Total ~53.8M floats ~ 215 MB.
    float* ws = (float*)d_ws;
    const size_t TOK = (size_t)M_ * Dm;      // 3,145,728
    float* xn   = ws;                         // dead after in_proj
    float* ao   = xn + TOK;                   // dead after attn_out gemm
    float* y    = xn;                         // aliases xn+ao (6.29M floats)
    float* qkv  = ao + TOK;                   // 9,437,184; dead after attention
    float* delta = qkv;                       // alias (6.29M <= 9.44M)
    float* xz   = qkv + (size_t)M_ * 2304;    // 12,582,912
    float* u    = xz + (size_t)M_ * 2 * DI;   // 6,291,456
    float* dbc  = u + (size_t)M_ * DI;        // 327,680
    float* attn_out = dbc + (size_t)M_ * 80;  // TOK
    float* ssm_out  = attn_out + TOK;         // TOK
    float* g    = ssm_out + TOK;              // TOK
    float* x1   = g + TOK;                    // TOK
    float* xn2  = x1 + TOK;                   // TOK
    float* rh   = xn2 + TOK;                  // 786,432
    float* sc   = rh + (size_t)M_ * 192;      // 4096
    int*   idxb = (int*)(sc + M_);            // 512 ints
    float* Xsel = sc + M_ + 512;              // 393,216
    float* Hsel = Xsel + (size_t)512 * Dm;    // 1,572,864
    float* proc = Hsel + (size_t)512 * DF;    // 393,216

    // 1. LN1
    ln_kernel<<<M_, 256, 0, stream>>>(x, ln1_w, ln1_b, xn);
    // 2. QKV projection (4096 x 2304 x 768)
    gemm_kernel<<<dim3(18, 32), 256, 0, stream>>>(xn, Dm, qkv_w, nullptr, qkv, M_, 2304, 768, 0, 0);
    // 3. RoPE in-place on q,k
    rope_kernel<<<(Bc * Sc * Hc * 32) / 256, 256, 0, stream>>>(qkv);
    // 4. Attention
    attn_kernel<<<dim3(Sc / 64, Bc * Hc), 64, 0, stream>>>(qkv, ao);
    // 5. attn_out projection
    gemm_kernel<<<dim3(6, 32), 256, 0, stream>>>(ao, Dm, attn_out_w, attn_out_b, attn_out, M_, 768, 768, 0, 0);
    // 6. in_proj (4096 x 3072 x 768)
    gemm_kernel<<<dim3(24, 32), 256, 0, stream>>>(xn, Dm, in_proj_w, nullptr, xz, M_, 2 * DI, 768, 0, 0);
    // 7. causal conv + SiLU -> u
    conv_silu_kernel<<<(M_ * DI) / 256, 256, 0, stream>>>(xz, conv_w, conv_b, u);
    // 8. x_proj (4096 x 80 x 1536)
    gemm_kernel<<<dim3(1, 32), 256, 0, stream>>>(u, DI, x_proj_w, nullptr, dbc, M_, 80, 1536, 0, 0);
    // 9. delta = softplus(dlow @ dt_w + dt_b)   (A = dbc cols 0..47, lda=80)
    gemm_kernel<<<dim3(12, 32), 256, 0, stream>>>(dbc, 80, dt_w, dt_b, delta, M_, DI, DTR, 1, 0);
    // 10. selective scan -> y (includes +u*D)
    scan_kernel<<<(Bc * DI * NST) / 256, 256, 0, stream>>>(delta, u, dbc, A_log, Dvec, y);
    // 11. y *= silu(z)
    ssmin_kernel<<<(M_ * DI) / 256, 256, 0, stream>>>(y, xz);
    // 12. ssm_out projection
    gemm_kernel<<<dim3(6, 32), 256, 0, stream>>>(y, DI, ssm_out_w, nullptr, ssm_out, M_, 768, 1536, 0, 0);
    // 13/14. gate: g = sigmoid(attn_out @ Wg[:768] + ssm_out @ Wg[768:] + b)
    gemm_kernel<<<dim3(6, 32), 256, 0, stream>>>(attn_out, Dm, gate_w, nullptr, g, M_, 768, 768, 0, 0);
    gemm_kernel<<<dim3(6, 32), 256, 0, stream>>>(ssm_out, Dm, gate_w + (size_t)768 * 768, gate_b, g, M_, 768, 768, 2, 1);
    // 15. x1
    x1_kernel<<<(M_ * Dm) / 256, 256, 0, stream>>>(x, g, attn_out, ssm_out, x1);
    // 16. LN2
    ln_kernel<<<M_, 256, 0, stream>>>(x1, ln2_w, ln2_b, xn2);
    // 17. router hidden (relu)
    gemm_kernel<<<dim3(2, 32), 256, 0, stream>>>(xn2, Dm, r_w1, r_b1, rh, M_, 192, 768, 3, 0);
    // 18. scores
    rowdot_kernel<<<M_ / 4, 256, 0, stream>>>(rh, r_w2, r_b2, sc);
    // 19. top-k
    topk_kernel<<<Bc, 256, 0, stream>>>(sc, idxb);
    // 20. gather selected
    gather_kernel<<<Bc * CAP, 256, 0, stream>>>(xn2, idxb, Xsel);
    // 21. FFN1 (gelu exact)
    gemm_kernel<<<dim3(24, 4), 256, 0, stream>>>(Xsel, Dm, ffn_w1, ffn_b1, Hsel, Bc * CAP, DF, 768, 4, 0);
    // 22. FFN2
    gemm_kernel<<<dim3(6, 4), 256, 0, stream>>>(Hsel, DF, ffn_w2, ffn_b2, proc, Bc * CAP, 768, DF, 0, 0);
    // 23. out = x1 + xn2
    finaladd_kernel<<<(M_ * Dm) / 256, 256, 0, stream>>>(x1, xn2, out);
    // 24. scatter selected: out = x1 + proc
    scatter_kernel<<<Bc * CAP, 256, 0, stream>>>(x1, proc, idxb, out);
}

// Round 3
// 4266.322 us; speedup vs baseline: 1.1852x; 1.1852x over previous
//
#include <hip/hip_runtime.h>
#include <cstdint>
#include <cstddef>

// Problem constants
constexpr int Bc   = 2;
constexpr int Sc   = 2048;
constexpr int Dm   = 768;
constexpr int Hc   = 12;
constexpr int HD   = 64;
constexpr int DI   = 1536;
constexpr int NST  = 16;
constexpr int DTR  = 48;
constexpr int CAP  = 256;   // 0.125 * S
constexpr int DF   = 3072;
constexpr int M_   = Bc * Sc;  // 4096 tokens
constexpr int NQ   = Bc * Hc * Sc;  // 49152 (b,h,s) query rows
constexpr int NCH  = 4;             // key chunks

// ---------------------------------------------------------------------------
// Activation codes: 0 none, 1 softplus, 2 sigmoid, 3 relu, 4 gelu(exact)
__device__ __forceinline__ float apply_act(float v, int act) {
    switch (act) {
        case 1: return (v > 20.f) ? v : log1pf(__expf(v));
        case 2: return 1.f / (1.f + __expf(-v));
        case 3: return fmaxf(v, 0.f);
        case 4: return 0.5f * v * (1.f + erff(v * 0.70710678118654752f));
        default: return v;
    }
}

// ---------------------------------------------------------------------------
// Generic fp32 GEMM: C[M,N] = act(acc*C + A[M,K](lda) @ W[K,N] + bias)
__global__ __launch_bounds__(256) void gemm_kernel(
    const float* __restrict__ A, int lda,
    const float* __restrict__ W,
    const float* __restrict__ bias,
    float* __restrict__ C,
    int M, int N, int K, int act, int accflag)
{
    __shared__ float As[16][132];
    __shared__ float Bs[16][132];
    const int tid = threadIdx.x;
    const int bm = blockIdx.y * 128;
    const int bn = blockIdx.x * 128;
    const int tx = tid & 15, ty = tid >> 4;

    float acc[8][8];
#pragma unroll
    for (int i = 0; i < 8; ++i)
#pragma unroll
        for (int j = 0; j < 8; ++j) acc[i][j] = 0.f;

    for (int k0 = 0; k0 < K; k0 += 16) {
#pragma unroll
        for (int i = 0; i < 2; ++i) {
            int f = tid + 256 * i;
            int row = f >> 2;
            int kc = (f & 3) * 4;
            const float* ap = A + (size_t)(bm + row) * lda + (k0 + kc);
            float4 v = *(const float4*)ap;
            As[kc + 0][row] = v.x; As[kc + 1][row] = v.y;
            As[kc + 2][row] = v.z; As[kc + 3][row] = v.w;
        }
#pragma unroll
        for (int i = 0; i < 2; ++i) {
            int f = tid + 256 * i;
            int row = f >> 5;
            int col = (f & 31) * 4;
            int gn = bn + col;
            const float* wp = W + (size_t)(k0 + row) * N + gn;
            float4 v;
            if (gn + 3 < N) v = *(const float4*)wp;
            else {
                v.x = (gn + 0 < N) ? wp[0] : 0.f;
                v.y = (gn + 1 < N) ? wp[1] : 0.f;
                v.z = (gn + 2 < N) ? wp[2] : 0.f;
                v.w = (gn + 3 < N) ? wp[3] : 0.f;
            }
            *(float4*)&Bs[row][col] = v;
        }
        __syncthreads();
#pragma unroll
        for (int kk = 0; kk < 16; ++kk) {
            float a[8], b[8];
            *(float4*)&a[0] = *(const float4*)&As[kk][ty * 4];
            *(float4*)&a[4] = *(const float4*)&As[kk][64 + ty * 4];
            *(float4*)&b[0] = *(const float4*)&Bs[kk][tx * 4];
            *(float4*)&b[4] = *(const float4*)&Bs[kk][64 + tx * 4];
#pragma unroll
            for (int i = 0; i < 8; ++i)
#pragma unroll
                for (int j = 0; j < 8; ++j)
                    acc[i][j] = fmaf(a[i], b[j], acc[i][j]);
        }
        __syncthreads();
    }

#pragma unroll
    for (int ii = 0; ii < 8; ++ii) {
        int row = bm + ((ii < 4) ? (ty * 4 + ii) : (64 + ty * 4 + ii - 4));
#pragma unroll
        for (int jj = 0; jj < 8; ++jj) {
            int col = bn + ((jj < 4) ? (tx * 4 + jj) : (64 + tx * 4 + jj - 4));
            if (col < N) {
                size_t cidx = (size_t)row * N + col;
                float v = acc[ii][jj];
                if (accflag) v += C[cidx];
                if (bias) v += bias[col];
                C[cidx] = apply_act(v, act);
            }
        }
    }
}

// ---------------------------------------------------------------------------
__global__ __launch_bounds__(256) void ln_kernel(
    const float* __restrict__ x, const float* __restrict__ w,
    const float* __restrict__ b, float* __restrict__ out)
{
    const int row = blockIdx.x, tid = threadIdx.x;
    const float* xp = x + (size_t)row * Dm;
    float v0 = xp[tid], v1 = xp[tid + 256], v2 = xp[tid + 512];
    float s1 = v0 + v1 + v2;
    float s2 = v0 * v0 + v1 * v1 + v2 * v2;
#pragma unroll
    for (int off = 32; off; off >>= 1) {
        s1 += __shfl_down(s1, off, 64);
        s2 += __shfl_down(s2, off, 64);
    }
    __shared__ float r1[4], r2[4];
    int wid = tid >> 6, lane = tid & 63;
    if (lane == 0) { r1[wid] = s1; r2[wid] = s2; }
    __syncthreads();
    s1 = r1[0] + r1[1] + r1[2] + r1[3];
    s2 = r2[0] + r2[1] + r2[2] + r2[3];
    float mu = s1 * (1.f / 768.f);
    float var = s2 * (1.f / 768.f) - mu * mu;
    float rstd = rsqrtf(var + 1e-5f);
    float* op = out + (size_t)row * Dm;
    op[tid]       = (v0 - mu) * rstd * w[tid]       + b[tid];
    op[tid + 256] = (v1 - mu) * rstd * w[tid + 256] + b[tid + 256];
    op[tid + 512] = (v2 - mu) * rstd * w[tid + 512] + b[tid + 512];
}

// ---------------------------------------------------------------------------
__global__ __launch_bounds__(256) void rope_kernel(float* __restrict__ qkv)
{
    int id = blockIdx.x * 256 + threadIdx.x;   // B*S*H*32
    int i = id & 31;
    int h = (id >> 5) % Hc;
    int r = id / (32 * Hc);        // b*S + s
    int s = r & (Sc - 1);
    float inv = powf(10000.f, -(float)(2 * i) * (1.f / 64.f));
    float f = (float)s * inv;
    float sn, cs;
    sincosf(f, &sn, &cs);
    float* base = qkv + (size_t)r * 2304 + h * 64 + i;
    float q1 = base[0], q2 = base[32];
    base[0]  = q1 * cs - q2 * sn;
    base[32] = q1 * sn + q2 * cs;
    float* kb = base + Dm;
    float k1 = kb[0], k2 = kb[32];
    kb[0]  = k1 * cs - k2 * sn;
    kb[32] = k1 * sn + k2 * cs;
}

// ---------------------------------------------------------------------------
// Flash-attention partial over a 512-key chunk.
// Block: 256 threads = 128 lane-pairs; pair p handles queries (2p, 2p+1);
// lane u=tid&1 holds dims [32u, 32u+32). Full dots via shfl_xor(.,1).
// Writes unnormalized o plus (m,l) per (chunk, query).
__global__ __launch_bounds__(256) void attn_partial_kernel(
    const float* __restrict__ qkv, float* __restrict__ po,
    float* __restrict__ pm, float* __restrict__ pl)
{
    __shared__ float Kt[64][64];
    __shared__ float Vt[64][64];
    const int tid = threadIdx.x;
    const int bh = blockIdx.y;              // 0..23
    const int b = bh / Hc, h = bh % Hc;
    const int chunk = blockIdx.z;           // 0..3
    const int u = tid & 1;
    const int pr = tid >> 1;                // 0..127
    const int sA = blockIdx.x * 256 + 2 * pr;

    float qA[32], qB[32], oA[32], oB[32];
    {
        const float* qpA = qkv + ((size_t)(b * Sc + sA)) * 2304 + h * 64 + 32 * u;
        const float* qpB = qpA + 2304;
#pragma unroll
        for (int i = 0; i < 8; ++i) {
            float4 a = *(const float4*)(qpA + 4 * i);
            float4 bb = *(const float4*)(qpB + 4 * i);
            qA[4*i+0] = a.x * 0.125f; qA[4*i+1] = a.y * 0.125f;
            qA[4*i+2] = a.z * 0.125f; qA[4*i+3] = a.w * 0.125f;
            qB[4*i+0] = bb.x * 0.125f; qB[4*i+1] = bb.y * 0.125f;
            qB[4*i+2] = bb.z * 0.125f; qB[4*i+3] = bb.w * 0.125f;
        }
    }
#pragma unroll
    for (int i = 0; i < 32; ++i) { oA[i] = 0.f; oB[i] = 0.f; }
    float mA = -1e30f, lA = 0.f, mB = -1e30f, lB = 0.f;

    const int k0base = chunk * 512;
    for (int kt = 0; kt < 512; kt += 64) {
        // stage 64 keys x 64 dims of K and V
#pragma unroll
        for (int i = 0; i < 8; ++i) {
            int f = tid + 256 * i;          // 0..2047
            int isV = f >> 10;              // 0:K 1:V
            int g = f & 1023;
            int row = g >> 4;
            int c4 = (g & 15) * 4;
            const float* src = qkv + ((size_t)(b * Sc + k0base + kt + row)) * 2304
                             + Dm + isV * Dm + h * 64 + c4;
            if (isV) *(float4*)&Vt[row][c4] = *(const float4*)src;
            else     *(float4*)&Kt[row][c4] = *(const float4*)src;
        }
        __syncthreads();

#pragma unroll 1
        for (int j0 = 0; j0 < 64; j0 += 8) {
            float pa[8], pb[8];
#pragma unroll
            for (int jj = 0; jj < 8; ++jj) {
                const float* kr = &Kt[j0 + jj][32 * u];
                float da0 = 0.f, da1 = 0.f, db0 = 0.f, db1 = 0.f;
#pragma unroll
                for (int c = 0; c < 4; ++c) {
                    float4 k1v = *(const float4*)(kr + 8 * c);
                    float4 k2v = *(const float4*)(kr + 8 * c + 4);
                    da0 += qA[8*c+0]*k1v.x + qA[8*c+1]*k1v.y + qA[8*c+2]*k1v.z + qA[8*c+3]*k1v.w;
                    da1 += qA[8*c+4]*k2v.x + qA[8*c+5]*k2v.y + qA[8*c+6]*k2v.z + qA[8*c+7]*k2v.w;
                    db0 += qB[8*c+0]*k1v.x + qB[8*c+1]*k1v.y + qB[8*c+2]*k1v.z + qB[8*c+3]*k1v.w;
                    db1 += qB[8*c+4]*k2v.x + qB[8*c+5]*k2v.y + qB[8*c+6]*k2v.z + qB[8*c+7]*k2v.w;
                }
                float da = da0 + da1;
                float db = db0 + db1;
                da += __shfl_xor(da, 1, 64);
                db += __shfl_xor(db, 1, 64);
                pa[jj] = da; pb[jj] = db;
            }
            // branchless online-softmax rescale, amortized over 8 keys
            float cmA = pa[0], cmB = pb[0];
#pragma unroll
            for (int jj = 1; jj < 8; ++jj) {
                cmA = fmaxf(cmA, pa[jj]); cmB = fmaxf(cmB, pb[jj]);
            }
            float nmA = fmaxf(mA, cmA), nmB = fmaxf(mB, cmB);
            float sfA = __expf(mA - nmA), sfB = __expf(mB - nmB);
            mA = nmA; mB = nmB;
            lA *= sfA; lB *= sfB;
#pragma unroll
            for (int i = 0; i < 32; ++i) { oA[i] *= sfA; oB[i] *= sfB; }
#pragma unroll
            for (int jj = 0; jj < 8; ++jj) {
                pa[jj] = __expf(pa[jj] - mA); lA += pa[jj];
                pb[jj] = __expf(pb[jj] - mB); lB += pb[jj];
            }
#pragma unroll
            for (int jj = 0; jj < 8; ++jj) {
                const float* vr = &Vt[j0 + jj][32 * u];
                float paj = pa[jj], pbj = pb[jj];
#pragma unroll
                for (int c = 0; c < 8; ++c) {
                    float4 vv = *(const float4*)(vr + 4 * c);
                    oA[4*c+0] += paj * vv.x; oA[4*c+1] += paj * vv.y;
                    oA[4*c+2] += paj * vv.z; oA[4*c+3] += paj * vv.w;
                    oB[4*c+0] += pbj * vv.x; oB[4*c+1] += pbj * vv.y;
                    oB[4*c+2] += pbj * vv.z; oB[4*c+3] += pbj * vv.w;
                }
            }
        }
        __syncthreads();
    }

    const size_t qiA = (size_t)bh * Sc + sA;
    const size_t qiB = qiA + 1;
    float* poA = po + ((size_t)chunk * NQ + qiA) * 64 + 32 * u;
    float* poB = po + ((size_t)chunk * NQ + qiB) * 64 + 32 * u;
#pragma unroll
    for (int i = 0; i < 8; ++i) {
        float4 t;
        t.x = oA[4*i+0]; t.y = oA[4*i+1]; t.z = oA[4*i+2]; t.w = oA[4*i+3];
        *(float4*)(poA + 4 * i) = t;
        t.x = oB[4*i+0]; t.y = oB[4*i+1]; t.z = oB[4*i+2]; t.w = oB[4*i+3];
        *(float4*)(poB + 4 * i) = t;
    }
    if (u == 0) {
        pm[(size_t)chunk * NQ + qiA] = mA;
        pl[(size_t)chunk * NQ + qiA] = lA;
        pm[(size_t)chunk * NQ + qiB] = mB;
        pl[(size_t)chunk * NQ + qiB] = lB;
    }
}

// Merge NCH partials -> ao (B,S,Dm). Block = 4 queries x 64 dims.
__global__ __launch_bounds__(256) void attn_combine_kernel(
    const float* __restrict__ po, const float* __restrict__ pm,
    const float* __restrict__ pl, float* __restrict__ ao)
{
    const int tid = threadIdx.x;
    const int d = tid & 63;
    const int qi = blockIdx.x * 4 + (tid >> 6);   // bh*Sc + s
    const int bh = qi >> 11;
    const int s = qi & (Sc - 1);
    const int b = bh / Hc, h = bh % Hc;
    float m0 = pm[qi], m1 = pm[NQ + qi], m2 = pm[2*NQ + qi], m3 = pm[3*NQ + qi];
    float M = fmaxf(fmaxf(m0, m1), fmaxf(m2, m3));
    float w0 = __expf(m0 - M), w1 = __expf(m1 - M);
    float w2 = __expf(m2 - M), w3 = __expf(m3 - M);
    float l = w0 * pl[qi] + w1 * pl[NQ + qi] + w2 * pl[2*NQ + qi] + w3 * pl[3*NQ + qi];
    float o = w0 * po[(size_t)qi * 64 + d]
            + w1 * po[((size_t)NQ + qi) * 64 + d]
            + w2 * po[((size_t)2*NQ + qi) * 64 + d]
            + w3 * po[((size_t)3*NQ + qi) * 64 + d];
    ao[((size_t)(b * Sc + s)) * Dm + h * 64 + d] = o / l;
}

// ---------------------------------------------------------------------------
__global__ __launch_bounds__(256) void conv_silu_kernel(
    const float* __restrict__ xz, const float* __restrict__ cw,
    const float* __restrict__ cb, float* __restrict__ u)
{
    int id = blockIdx.x * 256 + threadIdx.x;   // B*S*DI
    int d = id % DI;
    int r = id / DI;
    int s = r & (Sc - 1);
    int b = r >> 11;
    float acc = cb[d];
#pragma unroll
    for (int j = 0; j < 4; ++j) {
        int sp = s + j - 3;
        if (sp >= 0)
            acc += xz[((size_t)(b * Sc + sp)) * (2 * DI) + d] * cw[d * 4 + j];
    }
    u[id] = acc / (1.f + __expf(-acc));
}

// ---------------------------------------------------------------------------
__global__ __launch_bounds__(256) void scan_kernel(
    const float* __restrict__ delta, const float* __restrict__ u,
    const float* __restrict__ dbc, const float* __restrict__ A_log,
    const float* __restrict__ Dp, float* __restrict__ y)
{
    int gid = blockIdx.x * 256 + threadIdx.x;
    int n = gid & 15;
    int ch = gid >> 4;
    int b = ch / DI;
    int dd = ch - b * DI;
    float Av = -__expf(A_log[dd * NST + n]);
    float Dv = Dp[dd];
    const float* dp = delta + (size_t)b * Sc * DI + dd;
    const float* up = u     + (size_t)b * Sc * DI + dd;
    const float* Bp = dbc   + (size_t)b * Sc * 80 + DTR + n;
    const float* Cp = Bp + NST;
    float* yp = y + (size_t)b * Sc * DI + dd;

    float h = 0.f;
    constexpr int CH = 8;
    float cdt[CH], cu[CH], cB[CH], cC[CH];
    float ndt[CH], nu[CH], nB[CH], nC[CH];
#pragma unroll
    for (int i = 0; i < CH; ++i) {
        cdt[i] = dp[(size_t)i * DI]; cu[i] = up[(size_t)i * DI];
        cB[i] = Bp[(size_t)i * 80];  cC[i] = Cp[(size_t)i * 80];
    }
    for (int t0 = 0; t0 < Sc; t0 += CH) {
        bool more = (t0 + CH < Sc);
        if (more) {
#pragma unroll
            for (int i = 0; i < CH; ++i) {
                size_t t = t0 + CH + i;
                ndt[i] = dp[t * DI]; nu[i] = up[t * DI];
                nB[i] = Bp[t * 80];  nC[i] = Cp[t * 80];
            }
        }
#pragma unroll
        for (int i = 0; i < CH; ++i) {
            float dt = cdt[i];
            h = __expf(dt * Av) * h + dt * cu[i] * cB[i];
            float p = h * cC[i];
            p += __shfl_xor(p, 1, 16);
            p += __shfl_xor(p, 2, 16);
            p += __shfl_xor(p, 4, 16);
            p += __shfl_xor(p, 8, 16);
            if (n == 0) yp[(size_t)(t0 + i) * DI] = p + cu[i] * Dv;
        }
        if (more) {
#pragma unroll
            for (int i = 0; i < CH; ++i) {
                cdt[i] = ndt[i]; cu[i] = nu[i]; cB[i] = nB[i]; cC[i] = nC[i];
            }
        }
    }
}

// ---------------------------------------------------------------------------
__global__ __launch_bounds__(256) void ssmin_kernel(
    float* __restrict__ y, const float* __restrict__ xz)
{
    int id = blockIdx.x * 256 + threadIdx.x;
    int d = id % DI;
    int r = id / DI;
    float z = xz[(size_t)r * (2 * DI) + DI + d];
    y[id] = y[id] * (z / (1.f + __expf(-z)));
}

// ---------------------------------------------------------------------------
__global__ __launch_bounds__(256) void x1_kernel(
    const float* __restrict__ x, const float* __restrict__ g,
    const float* __restrict__ at, const float* __restrict__ sm,
    float* __restrict__ x1)
{
    int id = blockIdx.x * 256 + threadIdx.x;
    float gv = g[id];
    x1[id] = x[id] + gv * at[id] + (1.f - gv) * sm[id];
}

// ---------------------------------------------------------------------------
__global__ __launch_bounds__(256) void rowdot_kernel(
    const float* __restrict__ rh, const float* __restrict__ w2,
    const float* __restrict__ b2, float* __restrict__ sc)
{
    int lane = threadIdx.x & 63;
    int t = blockIdx.x * 4 + (threadIdx.x >> 6);
    const float* rp = rh + (size_t)t * 192;
    float sum = rp[lane] * w2[lane] + rp[lane + 64] * w2[lane + 64]
              + rp[lane + 128] * w2[lane + 128];
#pragma unroll
    for (int off = 32; off; off >>= 1) sum += __shfl_down(sum, off, 64);
    if (lane == 0) sc[t] = sum + b2[0];
}

// ---------------------------------------------------------------------------
__global__ __launch_bounds__(256) void topk_kernel(
    const float* __restrict__ sc, int* __restrict__ idxb)
{
    __shared__ float vals[Sc];
    __shared__ float rv[4];
    __shared__ int ri[4];
    const int b = blockIdx.x, tid = threadIdx.x;
    for (int i = tid; i < Sc; i += 256) vals[i] = sc[(size_t)b * Sc + i];
    __syncthreads();
    for (int it = 0; it < CAP; ++it) {
        float bv = -3.4e38f; int bi = 0x7fffffff;
        for (int i = tid; i < Sc; i += 256) {
            float v = vals[i];
            if (v > bv || (v == bv && i < bi)) { bv = v; bi = i; }
        }
#pragma unroll
        for (int off = 32; off; off >>= 1) {
            float ov = __shfl_down(bv, off, 64);
            int oi = __shfl_down(bi, off, 64);
            if (ov > bv || (ov == bv && oi < bi)) { bv = ov; bi = oi; }
        }
        int lane = tid & 63, wid = tid >> 6;
        if (lane == 0) { rv[wid] = bv; ri[wid] = bi; }
        __syncthreads();
        if (tid == 0) {
            float Bv = rv[0]; int Bi = ri[0];
            for (int w = 1; w < 4; ++w)
                if (rv[w] > Bv || (rv[w] == Bv && ri[w] < Bi)) { Bv = rv[w]; Bi = ri[w]; }
            idxb[b * CAP + it] = Bi;
            vals[Bi] = -3.4e38f;
        }
        __syncthreads();
    }
}

// ---------------------------------------------------------------------------
__global__ __launch_bounds__(256) void gather_kernel(
    const float* __restrict__ xn2, const int* __restrict__ idxb,
    float* __restrict__ Xsel)
{
    int i = blockIdx.x;
    int b = i >> 8;
    int t = idxb[i];
    const float* src = xn2 + ((size_t)(b * Sc + t)) * Dm;
    float* dst = Xsel + (size_t)i * Dm;
    int c = threadIdx.x;
    dst[c] = src[c]; dst[c + 256] = src[c + 256]; dst[c + 512] = src[c + 512];
}

__global__ __launch_bounds__(256) void finaladd_kernel(
    const float* __restrict__ x1, const float* __restrict__ xn2,
    float* __restrict__ out)
{
    int id = blockIdx.x * 256 + threadIdx.x;
    out[id] = x1[id] + xn2[id];
}

__global__ __launch_bounds__(256) void scatter_kernel(
    const float* __restrict__ x1, const float* __restrict__ proc,
    const int* __restrict__ idxb, float* __restrict__ out)
{
    int i = blockIdx.x;
    int b = i >> 8;
    int t = idxb[i];
    size_t ro = ((size_t)(b * Sc + t)) * Dm;
    const float* pp = proc + (size_t)i * Dm;
    int c = threadIdx.x;
    out[ro + c]       = x1[ro + c]       + pp[c];
    out[ro + c + 256] = x1[ro + c + 256] + pp[c + 256];
    out[ro + c + 512] = x1[ro + c + 512] + pp[c + 512];
}

// ---------------------------------------------------------------------------
extern "C" void kernel_launch(void* const* d_in, const int* in_sizes, int n_in,
                              void* d_out, int out_size, void* d_ws, size_t ws_size,
                              hipStream_t stream)
{
    (void)in_sizes; (void)n_in; (void)out_size; (void)ws_size;
    const float* x          = (const float*)d_in[0];
    const float* ln1_w      = (const float*)d_in[1];
    const float* ln1_b      = (const float*)d_in[2];
    const float* ln2_w      = (const float*)d_in[3];
    const float* ln2_b      = (const float*)d_in[4];
    const float* qkv_w      = (const float*)d_in[5];
    const float* attn_out_w = (const float*)d_in[6];
    const float* attn_out_b = (const float*)d_in[7];
    const float* in_proj_w  = (const float*)d_in[8];
    const float* conv_w     = (const float*)d_in[9];
    const float* conv_b     = (const float*)d_in[10];
    const float* x_proj_w   = (const float*)d_in[11];
    const float* dt_w       = (const float*)d_in[12];
    const float* dt_b       = (const float*)d_in[13];
    const float* A_log      = (const float*)d_in[14];
    const float* Dvec       = (const float*)d_in[15];
    const float* ssm_out_w  = (const float*)d_in[16];
    const float* gate_w     = (const float*)d_in[17];
    const float* gate_b     = (const float*)d_in[18];
    const float* ffn_w1     = (const float*)d_in[19];
    const float* ffn_b1     = (const float*)d_in[20];
    const float* ffn_w2     = (const float*)d_in[21];
    const float* ffn_b2     = (const float*)d_in[22];
    const float* r_w1       = (const float*)d_in[23];
    const float* r_b1       = (const float*)d_in[24];
    const float* r_w2       = (const float*)d_in[25];
    const float* r_b2       = (const float*)d_in[26];
    float* out = (float*)d_out;

    float* ws = (float*)d_ws;
    const size_t TOK = (size_t)M_ * Dm;
    float* xn   = ws;
    float* ao   = xn + TOK;
    float* y    = xn;                         // alias (scan output spans xn+ao)
    float* qkv  = ao + TOK;
    float* delta = qkv;                       // alias (after attention consumes qkv)
    float* xz   = qkv + (size_t)M_ * 2304;
    float* u    = xz + (size_t)M_ * 2 * DI;
    float* dbc  = u + (size_t)M_ * DI;
    float* attn_out = dbc + (size_t)M_ * 80;
    float* ssm_out  = attn_out + TOK;
    float* g    = ssm_out + TOK;
    float* x1   = g + TOK;
    float* xn2  = x1 + TOK;
    float* rh   = xn2 + TOK;
    float* sc   = rh + (size_t)M_ * 192;
    int*   idxb = (int*)(sc + M_);
    float* Xsel = sc + M_ + 512;
    float* Hsel = Xsel + (size_t)512 * Dm;
    float* proc = Hsel + (size_t)512 * DF;

    // Attention partial buffers: relocated to arenas that are provably dead
    // until after attn_combine consumes them.
    //  po : attn_out..x1 arena (4*TOK = NCH*NQ*64 floats exactly; first
    //       written later by the attn_out projection, gemm step 5)
    //  pm/pl : rh arena (786k floats >= 2*NCH*NQ = 393k; first written by
    //       the router gemm, step 17)
    float* po  = attn_out;
    float* pmb = rh;
    float* plb = rh + (size_t)NCH * NQ;

    // 1. LN1
    ln_kernel<<<M_, 256, 0, stream>>>(x, ln1_w, ln1_b, xn);
    // 2. QKV projection
    gemm_kernel<<<dim3(18, 32), 256, 0, stream>>>(xn, Dm, qkv_w, nullptr, qkv, M_, 2304, 768, 0, 0);
    // 3. RoPE
    rope_kernel<<<(Bc * Sc * Hc * 32) / 256, 256, 0, stream>>>(qkv);
    // 4. Attention: key-split partials + combine
    attn_partial_kernel<<<dim3(Sc / 256, Bc * Hc, NCH), 256, 0, stream>>>(qkv, po, pmb, plb);
    attn_combine_kernel<<<NQ / 4, 256, 0, stream>>>(po, pmb, plb, ao);
    // 5. attn_out projection (overwrites po arena start — po is dead now)
    gemm_kernel<<<dim3(6, 32), 256, 0, stream>>>(ao, Dm, attn_out_w, attn_out_b, attn_out, M_, 768, 768, 0, 0);
    // 6. in_proj
    gemm_kernel<<<dim3(24, 32), 256, 0, stream>>>(xn, Dm, in_proj_w, nullptr, xz, M_, 2 * DI, 768, 0, 0);
    // 7. causal conv + SiLU
    conv_silu_kernel<<<(M_ * DI) / 256, 256, 0, stream>>>(xz, conv_w, conv_b, u);
    // 8. x_proj
    gemm_kernel<<<dim3(1, 32), 256, 0, stream>>>(u, DI, x_proj_w, nullptr, dbc, M_, 80, 1536, 0, 0);
    // 9. delta
    gemm_kernel<<<dim3(12, 32), 256, 0, stream>>>(dbc, 80, dt_w, dt_b, delta, M_, DI, DTR, 1, 0);
    // 10. scan
    scan_kernel<<<(Bc * DI * NST) / 256, 256, 0, stream>>>(delta, u, dbc, A_log, Dvec, y);
    // 11. y *= silu(z)
    ssmin_kernel<<<(M_ * DI) / 256, 256, 0, stream>>>(y, xz);
    // 12. ssm_out
    gemm_kernel<<<dim3(6, 32), 256, 0, stream>>>(y, DI, ssm_out_w, nullptr, ssm_out, M_, 768, 1536, 0, 0);
    // 13/14. gate
    gemm_kernel<<<dim3(6, 32), 256, 0, stream>>>(attn_out, Dm, gate_w, nullptr, g, M_, 768, 768, 0, 0);
    gemm_kernel<<<dim3(6, 32), 256, 0, stream>>>(ssm_out, Dm, gate_w + (size_t)768 * 768, gate_b, g, M_, 768, 768, 2, 1);
    // 15. x1
    x1_kernel<<<(M_ * Dm) / 256, 256, 0, stream>>>(x, g, attn_out, ssm_out, x1);
    // 16. LN2
    ln_kernel<<<M_, 256, 0, stream>>>(x1, ln2_w, ln2_b, xn2);
    // 17. router hidden (overwrites pm/pl arena — dead since combine)
    gemm_kernel<<<dim3(2, 32), 256, 0, stream>>>(xn2, Dm, r_w1, r_b1, rh, M_, 192, 768, 3, 0);
    // 18. scores
    rowdot_kernel<<<M_ / 4, 256, 0, stream>>>(rh, r_w2, r_b2, sc);
    // 19. top-k
    topk_kernel<<<Bc, 256, 0, stream>>>(sc, idxb);
    // 20. gather
    gather_kernel<<<Bc * CAP, 256, 0, stream>>>(xn2, idxb, Xsel);
    // 21. FFN1
    gemm_kernel<<<dim3(24, 4), 256, 0, stream>>>(Xsel, Dm, ffn_w1, ffn_b1, Hsel, Bc * CAP, DF, 768, 4, 0);
    // 22. FFN2
    gemm_kernel<<<dim3(6, 4), 256, 0, stream>>>(Hsel, DF, ffn_w2, ffn_b2, proc, Bc * CAP, 768, DF, 0, 0);
    // 23. out = x1 + xn2
    finaladd_kernel<<<(M_ * Dm) / 256, 256, 0, stream>>>(x1, xn2, out);
    // 24. scatter
    scatter_kernel<<<Bc * CAP, 256, 0, stream>>>(x1, proc, idxb, out);
}